// Round 7
// baseline (1088.033 us; speedup 1.0000x reference)
//
#include <hip/hip_runtime.h>
#include <hip/hip_bf16.h>
#include <hip/hip_fp16.h>

#define D 128

typedef _Float16 h8 __attribute__((ext_vector_type(8)));
typedef float f4 __attribute__((ext_vector_type(4)));

// ---------------- CSR build ----------------

__global__ void hist_kernel(const int* __restrict__ dst, int* __restrict__ counts, int E) {
    for (int e = blockIdx.x * blockDim.x + threadIdx.x; e < E; e += gridDim.x * blockDim.x)
        atomicAdd(&counts[dst[e]], 1);
}

__global__ __launch_bounds__(256) void scan_block_sums(const int* __restrict__ counts,
                                                       int* __restrict__ bsums, int N) {
    __shared__ int sdata[256];
    int t = threadIdx.x;
    int idx = blockIdx.x * 256 + t;
    sdata[t] = (idx < N) ? counts[idx] : 0;
    __syncthreads();
    for (int s = 128; s > 0; s >>= 1) {
        if (t < s) sdata[t] += sdata[t + s];
        __syncthreads();
    }
    if (t == 0) bsums[blockIdx.x] = sdata[0];
}

__global__ __launch_bounds__(1024) void scan_single(int* __restrict__ bsums, int nb,
                                                    int* __restrict__ offsets, int N, int E) {
    __shared__ int sdata[1024];
    int t = threadIdx.x;
    int v = (t < nb) ? bsums[t] : 0;
    sdata[t] = v;
    __syncthreads();
    for (int off = 1; off < 1024; off <<= 1) {
        int u = (t >= off) ? sdata[t - off] : 0;
        __syncthreads();
        sdata[t] += u;
        __syncthreads();
    }
    if (t < nb) bsums[t] = sdata[t] - v;
    if (t == 0) offsets[N] = E;
}

// also initializes cursor[] (copy_cursor folded in)
__global__ __launch_bounds__(256) void scan_final(const int* __restrict__ counts,
                                                  const int* __restrict__ bprefix,
                                                  int* __restrict__ offsets,
                                                  int* __restrict__ cursor, int N) {
    __shared__ int sdata[256];
    int t = threadIdx.x;
    int idx = blockIdx.x * 256 + t;
    int c = (idx < N) ? counts[idx] : 0;
    sdata[t] = c;
    __syncthreads();
    for (int off = 1; off < 256; off <<= 1) {
        int u = (t >= off) ? sdata[t - off] : 0;
        __syncthreads();
        sdata[t] += u;
        __syncthreads();
    }
    if (idx < N) {
        int v = bprefix[blockIdx.x] + (sdata[t] - c);
        offsets[idx] = v;
        cursor[idx] = v;
    }
}

__global__ void fill_csr(const int* __restrict__ src, const int* __restrict__ dst,
                         int* __restrict__ cursor, int* __restrict__ csr, int E) {
    for (int e = blockIdx.x * blockDim.x + threadIdx.x; e < E; e += gridDim.x * blockDim.x) {
        int d = dst[e];
        int p = atomicAdd(&cursor[d], 1);
        csr[p] = src[e];
    }
}

// ---------------- weight pack (+ BN fold) ----------------
// Wp layout: [mat(2)][jt(8)][kt(4)][lane(64)][e(8)] fp16; frag for lane l:
// j = jt*16 + (l&15), k = kt*32 + (l>>4)*8 + e;  W' = sc[k]*W[k][j].
// cadd[j] = sum_k sh[k]*W[k][j] ; brp[j] = br[j] + sum_k sh[k]*Wr[k][j]

__global__ __launch_bounds__(256) void pack_weights(const float* __restrict__ W,
                                                    const float* __restrict__ Wr,
                                                    const float* __restrict__ br_in,
                                                    const float* __restrict__ bn_sc,
                                                    const float* __restrict__ bn_sh,
                                                    __half* __restrict__ Wp,
                                                    float* __restrict__ cadd,
                                                    float* __restrict__ brp) {
    int t = threadIdx.x;
    for (int slot = t; slot < 4096; slot += 256) {
        int lane = slot & 63;
        int kt = (slot >> 6) & 3;
        int jt = (slot >> 8) & 7;
        int mat = slot >> 11;
        const float* Wsel = mat ? Wr : W;
        int j = jt * 16 + (lane & 15);
        int kb = kt * 32 + (lane >> 4) * 8;
        __half tmp[8];
        #pragma unroll
        for (int e = 0; e < 8; ++e) {
            int k = kb + e;
            float w = Wsel[k * D + j];
            if (bn_sc) w *= bn_sc[k];
            tmp[e] = __float2half(w);
        }
        *(uint4*)&Wp[(size_t)slot * 8] = *(const uint4*)tmp;
    }
    if (t < D) {
        float c = 0.f, bb = br_in[t];
        if (bn_sh) {
            for (int k = 0; k < D; ++k) {
                float sh = bn_sh[k];
                c += sh * W[k * D + t];
                bb += sh * Wr[k * D + t];
            }
        }
        cadd[t] = c;
        brp[t] = bb;
    }
}

// ---------------- MFMA dual GEMM: m = x@W' + cadd ; r = relu(x@Wr' + brp) ----------------

template <bool XHALF>
__global__ __launch_bounds__(256) void gemm_mfma(const void* __restrict__ x,
                                                 const __half* __restrict__ Wp,
                                                 const float* __restrict__ cadd,
                                                 const float* __restrict__ brp,
                                                 __half* __restrict__ m,
                                                 __half* __restrict__ r, int N) {
    int wv = threadIdx.x >> 6, lane = threadIdx.x & 63;
    int tilebase = blockIdx.x * 64 + wv * 16;
    int kgrp = lane >> 4;
    int arow = tilebase + (lane & 15);
    bool rowok = arow < N;

    h8 a0v = 0, a1v = 0, a2v = 0, a3v = 0;
    if (rowok) {
        if constexpr (XHALF) {
            const __half* xp = (const __half*)x + (size_t)arow * D + kgrp * 8;
            a0v = *(const h8*)(xp + 0);
            a1v = *(const h8*)(xp + 32);
            a2v = *(const h8*)(xp + 64);
            a3v = *(const h8*)(xp + 96);
        } else {
            const float* xf = (const float*)x + (size_t)arow * D + kgrp * 8;
            #pragma unroll
            for (int kt = 0; kt < 4; ++kt) {
                f4 lo = *(const f4*)(xf + kt * 32);
                f4 hi = *(const f4*)(xf + kt * 32 + 4);
                h8 tv;
                tv[0] = (_Float16)lo[0]; tv[1] = (_Float16)lo[1];
                tv[2] = (_Float16)lo[2]; tv[3] = (_Float16)lo[3];
                tv[4] = (_Float16)hi[0]; tv[5] = (_Float16)hi[1];
                tv[6] = (_Float16)hi[2]; tv[7] = (_Float16)hi[3];
                if (kt == 0) a0v = tv; else if (kt == 1) a1v = tv;
                else if (kt == 2) a2v = tv; else a3v = tv;
            }
        }
    }

    f4 accm[8], accr[8];
    #pragma unroll
    for (int jt = 0; jt < 8; ++jt) { accm[jt] = 0; accr[jt] = 0; }

    const h8* wp = (const h8*)Wp;
    #pragma unroll
    for (int jt = 0; jt < 8; ++jt) {
        const h8* bm = wp + ((size_t)jt * 4) * 64 + lane;
        const h8* bw = wp + ((size_t)(8 + jt) * 4) * 64 + lane;
        accm[jt] = __builtin_amdgcn_mfma_f32_16x16x32_f16(a0v, bm[0 * 64], accm[jt], 0, 0, 0);
        accm[jt] = __builtin_amdgcn_mfma_f32_16x16x32_f16(a1v, bm[1 * 64], accm[jt], 0, 0, 0);
        accm[jt] = __builtin_amdgcn_mfma_f32_16x16x32_f16(a2v, bm[2 * 64], accm[jt], 0, 0, 0);
        accm[jt] = __builtin_amdgcn_mfma_f32_16x16x32_f16(a3v, bm[3 * 64], accm[jt], 0, 0, 0);
        accr[jt] = __builtin_amdgcn_mfma_f32_16x16x32_f16(a0v, bw[0 * 64], accr[jt], 0, 0, 0);
        accr[jt] = __builtin_amdgcn_mfma_f32_16x16x32_f16(a1v, bw[1 * 64], accr[jt], 0, 0, 0);
        accr[jt] = __builtin_amdgcn_mfma_f32_16x16x32_f16(a2v, bw[2 * 64], accr[jt], 0, 0, 0);
        accr[jt] = __builtin_amdgcn_mfma_f32_16x16x32_f16(a3v, bw[3 * 64], accr[jt], 0, 0, 0);
    }

    int j0 = lane & 15;
    int orow0 = tilebase + kgrp * 4;
    #pragma unroll
    for (int jt = 0; jt < 8; ++jt) {
        int j = jt * 16 + j0;
        float cm = cadd[j];
        float bb = brp[j];
        #pragma unroll
        for (int q = 0; q < 4; ++q) {
            int row = orow0 + q;
            if (row < N) {
                m[(size_t)row * D + j] = __float2half(accm[jt][q] + cm);
                r[(size_t)row * D + j] = __float2half(fmaxf(accr[jt][q] + bb, 0.f));
            }
        }
    }
}

// ---------------- column-split gather + combine + fused BN stats ----------------
// pass p covers dword-cols [p*32, p*32+32) (fp16 cols [p*64, p*64+64)).
// One node per wave; the two 32-lane halves gather DIFFERENT edges' half-rows
// (128B each) -> 2 edges per vmem instruction, 8 edges in flight at unroll 4.
// csr staged 64 edges at a time via one coalesced load + __shfl broadcast
// (shfl always executed with all 64 lanes active).

template <bool OHALF>
__global__ __launch_bounds__(256) void combine_split(const __half* __restrict__ m,
                                                     const int* __restrict__ csr,
                                                     const int* __restrict__ offsets,
                                                     const float* __restrict__ bias,
                                                     const __half* __restrict__ r,
                                                     void* __restrict__ out,
                                                     float* __restrict__ stats,
                                                     int N, int pass) {
    __shared__ float4 sred[4][32];
    int t = threadIdx.x;
    int wave = t >> 6, lane = t & 63;
    int hf = lane >> 5, l = lane & 31;
    int node = blockIdx.x * 4 + wave;
    int coloff = pass * 32 + l;  // dword index within 64-dword row

    float v0 = 0.f, v1 = 0.f;
    if (node < N) {
        int e0 = offsets[node], e1 = offsets[node + 1];
        const uint* mp = (const uint*)m;
        float a0 = 0.f, a1 = 0.f, b0 = 0.f, b1 = 0.f;
        float c0 = 0.f, c1 = 0.f, d0 = 0.f, d1 = 0.f;
        for (int base = e0; base < e1; base += 64) {
            int idx = 0;
            if (base + lane < e1) idx = csr[base + lane];
            int nav = min(64, e1 - base);
            int i = 0;
            int nfull = (nav >> 3) << 2;  // pair-instr count in full groups of 8 edges
            for (; i < nfull; i += 4) {
                int s0 = __shfl(idx, 2 * i + hf);
                int s1 = __shfl(idx, 2 * i + 2 + hf);
                int s2 = __shfl(idx, 2 * i + 4 + hf);
                int s3 = __shfl(idx, 2 * i + 6 + hf);
                uint p0 = mp[(size_t)s0 * 64 + coloff];
                uint p1 = mp[(size_t)s1 * 64 + coloff];
                uint p2 = mp[(size_t)s2 * 64 + coloff];
                uint p3 = mp[(size_t)s3 * 64 + coloff];
                float2 f0 = __half22float2(*reinterpret_cast<__half2*>(&p0));
                float2 f1 = __half22float2(*reinterpret_cast<__half2*>(&p1));
                float2 f2 = __half22float2(*reinterpret_cast<__half2*>(&p2));
                float2 f3 = __half22float2(*reinterpret_cast<__half2*>(&p3));
                a0 += f0.x; a1 += f0.y;
                b0 += f1.x; b1 += f1.y;
                c0 += f2.x; c1 += f2.y;
                d0 += f3.x; d1 += f3.y;
            }
            for (; 2 * i < nav; ++i) {  // tail pairs (uniform loop bound)
                int j = 2 * i + hf;
                int s = __shfl(idx, j);  // all lanes active; invalid j -> lane's idx==0, safe
                if (j < nav) {
                    uint p = mp[(size_t)s * 64 + coloff];
                    float2 f = __half22float2(*reinterpret_cast<__half2*>(&p));
                    a0 += f.x; a1 += f.y;
                }
            }
        }
        float sum0 = (a0 + b0) + (c0 + d0);
        float sum1 = (a1 + b1) + (c1 + d1);
        sum0 += __shfl_xor(sum0, 32);  // combine the two half-wave edge subsets
        sum1 += __shfl_xor(sum1, 32);
        uint rv = ((const uint*)r)[(size_t)node * 64 + coloff];
        float2 rf = __half22float2(*reinterpret_cast<__half2*>(&rv));
        float2 bv = *(const float2*)&bias[2 * coloff];
        v0 = fmaxf(sum0 + bv.x, 0.f) + rf.x;
        v1 = fmaxf(sum1 + bv.y, 0.f) + rf.y;
        if (hf == 0) {
            if constexpr (OHALF) {
                __half2 hv = __floats2half2_rn(v0, v1);
                ((uint*)out)[(size_t)node * 64 + coloff] = *reinterpret_cast<uint*>(&hv);
            } else {
                *(float2*)&((float*)out)[(size_t)node * D + 2 * coloff] = make_float2(v0, v1);
            }
        }
    }
    if (hf == 0) sred[wave][l] = make_float4(v0, v1, v0 * v0, v1 * v1);
    __syncthreads();
    if (wave == 0) {
        float4 q0 = sred[0][l], q1 = sred[1][l], q2 = sred[2][l], q3 = sred[3][l];
        int copy = blockIdx.x & 7;
        int col = pass * 64 + 2 * l;
        if (hf == 0) {
            float* ss = &stats[copy * 128 + col];
            atomicAdd(&ss[0], q0.x + q1.x + q2.x + q3.x);
            atomicAdd(&ss[1], q0.y + q1.y + q2.y + q3.y);
        } else {
            float* sq = &stats[1024 + copy * 128 + col];
            atomicAdd(&sq[0], q0.z + q1.z + q2.z + q3.z);
            atomicAdd(&sq[1], q0.w + q1.w + q2.w + q3.w);
        }
    }
}

// ---------------- BatchNorm finalize / apply ----------------

__global__ void bn_finalize(float* __restrict__ stats, const float* __restrict__ g,
                            const float* __restrict__ be, float invN) {
    int j = threadIdx.x;  // 128
    float s = 0.f, q = 0.f;
    #pragma unroll
    for (int c = 0; c < 8; ++c) {
        s += stats[c * 128 + j];
        q += stats[1024 + c * 128 + j];
    }
    float mu = s * invN;
    float var = q * invN - mu * mu;
    float sc = g[j] * rsqrtf(var + 1e-5f);
    stats[2048 + j] = sc;
    stats[2048 + 128 + j] = be[j] - mu * sc;
}

__global__ __launch_bounds__(256) void bn_apply(float* __restrict__ buf,
                                                const float* __restrict__ stats, int n4) {
    for (int i = blockIdx.x * blockDim.x + threadIdx.x; i < n4; i += gridDim.x * blockDim.x) {
        float4 v = ((const float4*)buf)[i];
        int c0 = (i * 4) & 127;
        float4 sc = *(const float4*)&stats[2048 + c0];
        float4 sh = *(const float4*)&stats[2048 + 128 + c0];
        v.x = v.x * sc.x + sh.x;
        v.y = v.y * sc.y + sh.y;
        v.z = v.z * sc.z + sh.z;
        v.w = v.w * sc.w + sh.w;
        ((float4*)buf)[i] = v;
    }
}

// ---------------- host ----------------

static inline char* align_up(char* p, size_t a) {
    return (char*)(((uintptr_t)p + (a - 1)) & ~(uintptr_t)(a - 1));
}

extern "C" void kernel_launch(void* const* d_in, const int* in_sizes, int n_in,
                              void* d_out, int out_size, void* d_ws, size_t ws_size,
                              hipStream_t stream) {
    const float* h   = (const float*)d_in[0];
    const int*   src = (const int*)d_in[1];
    const int*   dst = (const int*)d_in[2];
    const float* W0  = (const float*)d_in[3];
    const float* b0  = (const float*)d_in[4];
    const float* Wr0 = (const float*)d_in[5];
    const float* br0 = (const float*)d_in[6];
    const float* g0  = (const float*)d_in[7];
    const float* be0 = (const float*)d_in[8];
    const float* W1  = (const float*)d_in[9];
    const float* b1  = (const float*)d_in[10];
    const float* Wr1 = (const float*)d_in[11];
    const float* br1 = (const float*)d_in[12];
    const float* g1  = (const float*)d_in[13];
    const float* be1 = (const float*)d_in[14];

    const int N = in_sizes[0] / D;
    const int E = in_sizes[1];
    float* out = (float*)d_out;

    // workspace layout
    char* p = (char*)d_ws;
    __half* m_buf  = (__half*)p;              p += (size_t)N * D * sizeof(__half);
    p = align_up(p, 256);
    __half* x1_buf = (__half*)p;              p += (size_t)N * D * sizeof(__half);
    p = align_up(p, 256);
    __half* r_buf  = (__half*)p;              p += (size_t)N * D * sizeof(__half);
    p = align_up(p, 256);
    int* counts  = (int*)p;                   p += (size_t)N * sizeof(int);
    p = align_up(p, 256);
    int* offsets = (int*)p;                   p += (size_t)(N + 1) * sizeof(int);
    p = align_up(p, 256);
    int* cursor  = (int*)p;                   p += (size_t)N * sizeof(int);
    p = align_up(p, 256);
    int* bsums   = (int*)p;                   p += 1024 * sizeof(int);
    p = align_up(p, 256);
    int* csr     = (int*)p;                   p += (size_t)E * sizeof(int);
    p = align_up(p, 256);
    float* stats1 = (float*)p;                p += 2304 * sizeof(float);
    p = align_up(p, 256);
    float* stats2 = (float*)p;                p += 2304 * sizeof(float);
    p = align_up(p, 256);
    __half* Wp0 = (__half*)p;                 p += 32768 * sizeof(__half);
    p = align_up(p, 256);
    __half* Wp1 = (__half*)p;                 p += 32768 * sizeof(__half);
    p = align_up(p, 256);
    float* cadd0 = (float*)p;                 p += D * sizeof(float);
    float* brp0  = (float*)p;                 p += D * sizeof(float);
    float* cadd1 = (float*)p;                 p += D * sizeof(float);
    float* brp1  = (float*)p;                 p += D * sizeof(float);
    (void)ws_size;

    const int nb = (N + 255) / 256;
    const float invN = 1.0f / (float)N;

    // ---- CSR build (shared across both layers) ----
    hipMemsetAsync(counts, 0, (size_t)N * sizeof(int), stream);
    hist_kernel<<<2048, 256, 0, stream>>>(dst, counts, E);
    scan_block_sums<<<nb, 256, 0, stream>>>(counts, bsums, N);
    scan_single<<<1, 1024, 0, stream>>>(bsums, nb, offsets, N, E);
    scan_final<<<nb, 256, 0, stream>>>(counts, bsums, offsets, cursor, N);
    fill_csr<<<2048, 256, 0, stream>>>(src, dst, cursor, csr, E);

    const int gemm_grid = (N + 63) / 64;
    const int comb_grid = (N + 3) / 4;
    const int n4 = N * D / 4;

    // ---- layer 1: h (fp32) -> x1_buf (fp16 raw; its BN folded into layer-2 weights) ----
    pack_weights<<<1, 256, 0, stream>>>(W0, Wr0, br0, nullptr, nullptr, Wp0, cadd0, brp0);
    gemm_mfma<false><<<gemm_grid, 256, 0, stream>>>(h, Wp0, cadd0, brp0, m_buf, r_buf, N);
    hipMemsetAsync(stats1, 0, 2048 * sizeof(float), stream);
    combine_split<true><<<comb_grid, 256, 0, stream>>>(m_buf, csr, offsets, b0, r_buf,
                                                       x1_buf, stats1, N, 0);
    combine_split<true><<<comb_grid, 256, 0, stream>>>(m_buf, csr, offsets, b0, r_buf,
                                                       x1_buf, stats1, N, 1);
    bn_finalize<<<1, D, 0, stream>>>(stats1, g0, be0, invN);

    // ---- layer 2: x1_buf (fp16 raw) -> out (fp32); BN1 folded into Wp1/cadd1/brp1 ----
    pack_weights<<<1, 256, 0, stream>>>(W1, Wr1, br1, stats1 + 2048, stats1 + 2048 + 128,
                                        Wp1, cadd1, brp1);
    gemm_mfma<true><<<gemm_grid, 256, 0, stream>>>(x1_buf, Wp1, cadd1, brp1, m_buf, r_buf, N);
    hipMemsetAsync(stats2, 0, 2048 * sizeof(float), stream);
    combine_split<false><<<comb_grid, 256, 0, stream>>>(m_buf, csr, offsets, b1, r_buf,
                                                        out, stats2, N, 0);
    combine_split<false><<<comb_grid, 256, 0, stream>>>(m_buf, csr, offsets, b1, r_buf,
                                                        out, stats2, N, 1);
    bn_finalize<<<1, D, 0, stream>>>(stats2, g1, be1, invN);
    bn_apply<<<2048, 256, 0, stream>>>(out, stats2, n4);
}

// Round 9
// 703.897 us; speedup vs baseline: 1.5457x; 1.5457x over previous
//
#include <hip/hip_runtime.h>
#include <hip/hip_bf16.h>
#include <hip/hip_fp16.h>

#define D 128

typedef _Float16 h8 __attribute__((ext_vector_type(8)));
typedef float f4 __attribute__((ext_vector_type(4)));

// ---------------- CSR build ----------------

__global__ void hist_kernel(const int* __restrict__ dst, int* __restrict__ counts, int E) {
    for (int e = blockIdx.x * blockDim.x + threadIdx.x; e < E; e += gridDim.x * blockDim.x)
        atomicAdd(&counts[dst[e]], 1);
}

__global__ __launch_bounds__(256) void scan_block_sums(const int* __restrict__ counts,
                                                       int* __restrict__ bsums, int N) {
    __shared__ int sdata[256];
    int t = threadIdx.x;
    int idx = blockIdx.x * 256 + t;
    sdata[t] = (idx < N) ? counts[idx] : 0;
    __syncthreads();
    for (int s = 128; s > 0; s >>= 1) {
        if (t < s) sdata[t] += sdata[t + s];
        __syncthreads();
    }
    if (t == 0) bsums[blockIdx.x] = sdata[0];
}

__global__ __launch_bounds__(1024) void scan_single(int* __restrict__ bsums, int nb,
                                                    int* __restrict__ offsets, int N, int E) {
    __shared__ int sdata[1024];
    int t = threadIdx.x;
    int v = (t < nb) ? bsums[t] : 0;
    sdata[t] = v;
    __syncthreads();
    for (int off = 1; off < 1024; off <<= 1) {
        int u = (t >= off) ? sdata[t - off] : 0;
        __syncthreads();
        sdata[t] += u;
        __syncthreads();
    }
    if (t < nb) bsums[t] = sdata[t] - v;
    if (t == 0) offsets[N] = E;
}

// also initializes cursor[] (copy_cursor folded in)
__global__ __launch_bounds__(256) void scan_final(const int* __restrict__ counts,
                                                  const int* __restrict__ bprefix,
                                                  int* __restrict__ offsets,
                                                  int* __restrict__ cursor, int N) {
    __shared__ int sdata[256];
    int t = threadIdx.x;
    int idx = blockIdx.x * 256 + t;
    int c = (idx < N) ? counts[idx] : 0;
    sdata[t] = c;
    __syncthreads();
    for (int off = 1; off < 256; off <<= 1) {
        int u = (t >= off) ? sdata[t - off] : 0;
        __syncthreads();
        sdata[t] += u;
        __syncthreads();
    }
    if (idx < N) {
        int v = bprefix[blockIdx.x] + (sdata[t] - c);
        offsets[idx] = v;
        cursor[idx] = v;
    }
}

__global__ void fill_csr(const int* __restrict__ src, const int* __restrict__ dst,
                         int* __restrict__ cursor, int* __restrict__ csr, int E) {
    for (int e = blockIdx.x * blockDim.x + threadIdx.x; e < E; e += gridDim.x * blockDim.x) {
        int d = dst[e];
        int p = atomicAdd(&cursor[d], 1);
        csr[p] = src[e];
    }
}

// ---------------- fp32 -> fp16 convert ----------------

__global__ __launch_bounds__(256) void convert_f16(const float* __restrict__ in,
                                                   __half* __restrict__ out, int n4) {
    for (int i = blockIdx.x * blockDim.x + threadIdx.x; i < n4; i += gridDim.x * blockDim.x) {
        float4 v = ((const float4*)in)[i];
        __half2 h0 = __floats2half2_rn(v.x, v.y);
        __half2 h1 = __floats2half2_rn(v.z, v.w);
        uint2 u;
        u.x = *reinterpret_cast<uint*>(&h0);
        u.y = *reinterpret_cast<uint*>(&h1);
        ((uint2*)out)[i] = u;
    }
}

// ---------------- weight pack (+ BN fold) ----------------
// Wp layout: [mat(2)][jt(8)][kt(4)][lane(64)][e(8)] fp16; frag for lane l:
// j = jt*16 + (l&15), k = kt*32 + (l>>4)*8 + e;  W' = sc[k]*W[k][j].
// cadd[j] = sum_k sh[k]*W[k][j] (scaled by node degree at use site)
// brp[j]  = br[j] + sum_k sh[k]*Wr[k][j]

__global__ __launch_bounds__(256) void pack_weights(const float* __restrict__ W,
                                                    const float* __restrict__ Wr,
                                                    const float* __restrict__ br_in,
                                                    const float* __restrict__ bn_sc,
                                                    const float* __restrict__ bn_sh,
                                                    __half* __restrict__ Wp,
                                                    float* __restrict__ cadd,
                                                    float* __restrict__ brp) {
    int t = threadIdx.x;
    for (int slot = t; slot < 4096; slot += 256) {
        int lane = slot & 63;
        int kt = (slot >> 6) & 3;
        int jt = (slot >> 8) & 7;
        int mat = slot >> 11;
        const float* Wsel = mat ? Wr : W;
        int j = jt * 16 + (lane & 15);
        int kb = kt * 32 + (lane >> 4) * 8;
        __half tmp[8];
        #pragma unroll
        for (int e = 0; e < 8; ++e) {
            int k = kb + e;
            float w = Wsel[k * D + j];
            if (bn_sc) w *= bn_sc[k];
            tmp[e] = __float2half(w);
        }
        *(uint4*)&Wp[(size_t)slot * 8] = *(const uint4*)tmp;
    }
    if (t < D) {
        float c = 0.f, bb = br_in[t];
        if (bn_sh) {
            for (int k = 0; k < D; ++k) {
                float sh = bn_sh[k];
                c += sh * W[k * D + t];
                bb += sh * Wr[k * D + t];
            }
        }
        cadd[t] = c;
        brp[t] = bb;
    }
}

// ---------------- pure gather-sum: agg[dst] = sum_{src in in(dst)} x[src] ----------------
// Round-2 proven shape: one node per 64-lane wave, 1 dword (2 fp16 cols)/lane/edge,
// 2 independent edges in flight, fp32 accumulate, named scalar accumulators.

__global__ __launch_bounds__(256) void gather_sum(const __half* __restrict__ x,
                                                  const int* __restrict__ csr,
                                                  const int* __restrict__ offsets,
                                                  __half* __restrict__ agg, int N) {
    int t = threadIdx.x;
    int wave = t >> 6, lane = t & 63;
    int node = blockIdx.x * 4 + wave;
    if (node >= N) return;
    int e0 = offsets[node], e1 = offsets[node + 1];
    const uint* mp = (const uint*)x;  // row = 64 dwords (128 fp16)
    float a0 = 0.f, a1 = 0.f, c0 = 0.f, c1 = 0.f;
    int e = e0;
    for (; e + 2 <= e1; e += 2) {
        int s0 = csr[e], s1 = csr[e + 1];
        uint p0 = mp[(size_t)s0 * 64 + lane];
        uint p1 = mp[(size_t)s1 * 64 + lane];
        float2 f0 = __half22float2(*reinterpret_cast<__half2*>(&p0));
        float2 f1 = __half22float2(*reinterpret_cast<__half2*>(&p1));
        a0 += f0.x; a1 += f0.y;
        c0 += f1.x; c1 += f1.y;
    }
    if (e < e1) {
        int s = csr[e];
        uint p = mp[(size_t)s * 64 + lane];
        float2 f = __half22float2(*reinterpret_cast<__half2*>(&p));
        a0 += f.x; a1 += f.y;
    }
    __half2 hv = __floats2half2_rn(a0 + c0, a1 + c1);
    ((uint*)agg)[(size_t)node * 64 + lane] = *reinterpret_cast<uint*>(&hv);
}

// ---------------- fused MFMA layer: out = relu(agg@W'+deg*cadd+b) + relu(x@Wr'+brp) ----
// + BN col-stats (sum, sumsq) reduced in epilogue -> 8-replica atomics.

template <bool OHALF>
__global__ __launch_bounds__(256) void gemm_fused(const __half* __restrict__ x,
                                                  const __half* __restrict__ agg,
                                                  const __half* __restrict__ Wp,
                                                  const float* __restrict__ cadd,
                                                  const float* __restrict__ brp,
                                                  const float* __restrict__ bvec,
                                                  const int* __restrict__ counts,
                                                  void* __restrict__ outbuf,
                                                  float* __restrict__ stats, int N) {
    __shared__ float sds[4][8][16];
    __shared__ float sdq[4][8][16];
    int wv = threadIdx.x >> 6, lane = threadIdx.x & 63;
    int tilebase = blockIdx.x * 64 + wv * 16;
    int kgrp = lane >> 4, j0 = lane & 15;
    int arow = tilebase + j0;
    bool rowok = arow < N;

    h8 ax0 = 0, ax1 = 0, ax2 = 0, ax3 = 0;   // x fragments
    h8 ag0 = 0, ag1 = 0, ag2 = 0, ag3 = 0;   // agg fragments
    if (rowok) {
        const __half* xp = x + (size_t)arow * D + kgrp * 8;
        ax0 = *(const h8*)(xp + 0);
        ax1 = *(const h8*)(xp + 32);
        ax2 = *(const h8*)(xp + 64);
        ax3 = *(const h8*)(xp + 96);
        const __half* ap = agg + (size_t)arow * D + kgrp * 8;
        ag0 = *(const h8*)(ap + 0);
        ag1 = *(const h8*)(ap + 32);
        ag2 = *(const h8*)(ap + 64);
        ag3 = *(const h8*)(ap + 96);
    }

    f4 accm[8], accr[8];
    #pragma unroll
    for (int jt = 0; jt < 8; ++jt) { accm[jt] = 0; accr[jt] = 0; }

    const h8* wp = (const h8*)Wp;
    #pragma unroll
    for (int jt = 0; jt < 8; ++jt) {
        const h8* bm = wp + ((size_t)jt * 4) * 64 + lane;          // W'  (agg path)
        const h8* bw = wp + ((size_t)(8 + jt) * 4) * 64 + lane;    // Wr' (x path)
        accm[jt] = __builtin_amdgcn_mfma_f32_16x16x32_f16(ag0, bm[0 * 64], accm[jt], 0, 0, 0);
        accm[jt] = __builtin_amdgcn_mfma_f32_16x16x32_f16(ag1, bm[1 * 64], accm[jt], 0, 0, 0);
        accm[jt] = __builtin_amdgcn_mfma_f32_16x16x32_f16(ag2, bm[2 * 64], accm[jt], 0, 0, 0);
        accm[jt] = __builtin_amdgcn_mfma_f32_16x16x32_f16(ag3, bm[3 * 64], accm[jt], 0, 0, 0);
        accr[jt] = __builtin_amdgcn_mfma_f32_16x16x32_f16(ax0, bw[0 * 64], accr[jt], 0, 0, 0);
        accr[jt] = __builtin_amdgcn_mfma_f32_16x16x32_f16(ax1, bw[1 * 64], accr[jt], 0, 0, 0);
        accr[jt] = __builtin_amdgcn_mfma_f32_16x16x32_f16(ax2, bw[2 * 64], accr[jt], 0, 0, 0);
        accr[jt] = __builtin_amdgcn_mfma_f32_16x16x32_f16(ax3, bw[3 * 64], accr[jt], 0, 0, 0);
    }

    // D layout: col = jt*16 + j0, rows = tilebase + kgrp*4 + q
    int orow0 = tilebase + kgrp * 4;
    float dg[4];
    #pragma unroll
    for (int q = 0; q < 4; ++q) {
        int row = orow0 + q;
        dg[q] = (row < N) ? (float)counts[row] : 0.f;
    }

    float ls[8], lq[8];
    #pragma unroll
    for (int jt = 0; jt < 8; ++jt) {
        int j = jt * 16 + j0;
        float cm = cadd[j];
        float bb = brp[j];
        float bj = bvec[j];
        float s = 0.f, qq = 0.f;
        #pragma unroll
        for (int q = 0; q < 4; ++q) {
            int row = orow0 + q;
            float o = 0.f;
            if (row < N) {
                float nw = fmaxf(accm[jt][q] + dg[q] * cm + bj, 0.f);
                float rs = fmaxf(accr[jt][q] + bb, 0.f);
                o = nw + rs;
                if constexpr (OHALF) {
                    ((__half*)outbuf)[(size_t)row * D + j] = __float2half(o);
                } else {
                    ((float*)outbuf)[(size_t)row * D + j] = o;
                }
            }
            s += o;
            qq += o * o;
        }
        ls[jt] = s;
        lq[jt] = qq;
    }

    // reduce across the 4 kgrp groups (lanes sharing j0)
    #pragma unroll
    for (int jt = 0; jt < 8; ++jt) {
        ls[jt] += __shfl_xor(ls[jt], 16);
        ls[jt] += __shfl_xor(ls[jt], 32);
        lq[jt] += __shfl_xor(lq[jt], 16);
        lq[jt] += __shfl_xor(lq[jt], 32);
    }
    if (lane < 16) {
        #pragma unroll
        for (int jt = 0; jt < 8; ++jt) {
            sds[wv][jt][j0] = ls[jt];
            sdq[wv][jt][j0] = lq[jt];
        }
    }
    __syncthreads();
    int tt = threadIdx.x;
    if (tt < 128) {
        int jj0 = tt & 15, jjt = tt >> 4;
        float s = sds[0][jjt][jj0] + sds[1][jjt][jj0] + sds[2][jjt][jj0] + sds[3][jjt][jj0];
        float q = sdq[0][jjt][jj0] + sdq[1][jjt][jj0] + sdq[2][jjt][jj0] + sdq[3][jjt][jj0];
        int copy = blockIdx.x & 7;
        atomicAdd(&stats[copy * 128 + tt], s);
        atomicAdd(&stats[1024 + copy * 128 + tt], q);
    }
}

// ---------------- BatchNorm finalize / apply ----------------

__global__ void bn_finalize(float* __restrict__ stats, const float* __restrict__ g,
                            const float* __restrict__ be, float invN) {
    int j = threadIdx.x;  // 128
    float s = 0.f, q = 0.f;
    #pragma unroll
    for (int c = 0; c < 8; ++c) {
        s += stats[c * 128 + j];
        q += stats[1024 + c * 128 + j];
    }
    float mu = s * invN;
    float var = q * invN - mu * mu;
    float sc = g[j] * rsqrtf(var + 1e-5f);
    stats[2048 + j] = sc;
    stats[2048 + 128 + j] = be[j] - mu * sc;
}

__global__ __launch_bounds__(256) void bn_apply(float* __restrict__ buf,
                                                const float* __restrict__ stats, int n4) {
    for (int i = blockIdx.x * blockDim.x + threadIdx.x; i < n4; i += gridDim.x * blockDim.x) {
        float4 v = ((const float4*)buf)[i];
        int c0 = (i * 4) & 127;
        float4 sc = *(const float4*)&stats[2048 + c0];
        float4 sh = *(const float4*)&stats[2048 + 128 + c0];
        v.x = v.x * sc.x + sh.x;
        v.y = v.y * sc.y + sh.y;
        v.z = v.z * sc.z + sh.z;
        v.w = v.w * sc.w + sh.w;
        ((float4*)buf)[i] = v;
    }
}

// ---------------- host ----------------

static inline char* align_up(char* p, size_t a) {
    return (char*)(((uintptr_t)p + (a - 1)) & ~(uintptr_t)(a - 1));
}

extern "C" void kernel_launch(void* const* d_in, const int* in_sizes, int n_in,
                              void* d_out, int out_size, void* d_ws, size_t ws_size,
                              hipStream_t stream) {
    const float* h   = (const float*)d_in[0];
    const int*   src = (const int*)d_in[1];
    const int*   dst = (const int*)d_in[2];
    const float* W0  = (const float*)d_in[3];
    const float* b0  = (const float*)d_in[4];
    const float* Wr0 = (const float*)d_in[5];
    const float* br0 = (const float*)d_in[6];
    const float* g0  = (const float*)d_in[7];
    const float* be0 = (const float*)d_in[8];
    const float* W1  = (const float*)d_in[9];
    const float* b1  = (const float*)d_in[10];
    const float* Wr1 = (const float*)d_in[11];
    const float* br1 = (const float*)d_in[12];
    const float* g1  = (const float*)d_in[13];
    const float* be1 = (const float*)d_in[14];

    const int N = in_sizes[0] / D;
    const int E = in_sizes[1];
    float* out = (float*)d_out;

    // workspace layout
    char* p = (char*)d_ws;
    __half* x0_buf = (__half*)p;              p += (size_t)N * D * sizeof(__half);
    p = align_up(p, 256);
    __half* x1_buf = (__half*)p;              p += (size_t)N * D * sizeof(__half);
    p = align_up(p, 256);
    __half* agg_buf = (__half*)p;             p += (size_t)N * D * sizeof(__half);
    p = align_up(p, 256);
    int* counts  = (int*)p;                   p += (size_t)N * sizeof(int);
    p = align_up(p, 256);
    int* offsets = (int*)p;                   p += (size_t)(N + 1) * sizeof(int);
    p = align_up(p, 256);
    int* cursor  = (int*)p;                   p += (size_t)N * sizeof(int);
    p = align_up(p, 256);
    int* bsums   = (int*)p;                   p += 1024 * sizeof(int);
    p = align_up(p, 256);
    int* csr     = (int*)p;                   p += (size_t)E * sizeof(int);
    p = align_up(p, 256);
    float* stats1 = (float*)p;                p += 2304 * sizeof(float);
    p = align_up(p, 256);
    float* stats2 = (float*)p;                p += 2304 * sizeof(float);
    p = align_up(p, 256);
    __half* Wp0 = (__half*)p;                 p += 32768 * sizeof(__half);
    p = align_up(p, 256);
    __half* Wp1 = (__half*)p;                 p += 32768 * sizeof(__half);
    p = align_up(p, 256);
    float* cadd0 = (float*)p;                 p += D * sizeof(float);
    float* brp0  = (float*)p;                 p += D * sizeof(float);
    float* cadd1 = (float*)p;                 p += D * sizeof(float);
    float* brp1  = (float*)p;                 p += D * sizeof(float);
    (void)ws_size;

    const int nb = (N + 255) / 256;
    const float invN = 1.0f / (float)N;

    // ---- input convert fp32 -> fp16 ----
    convert_f16<<<2048, 256, 0, stream>>>(h, x0_buf, N * D / 4);

    // ---- CSR build (shared across both layers; counts doubles as degree) ----
    hipMemsetAsync(counts, 0, (size_t)N * sizeof(int), stream);
    hist_kernel<<<2048, 256, 0, stream>>>(dst, counts, E);
    scan_block_sums<<<nb, 256, 0, stream>>>(counts, bsums, N);
    scan_single<<<1, 1024, 0, stream>>>(bsums, nb, offsets, N, E);
    scan_final<<<nb, 256, 0, stream>>>(counts, bsums, offsets, cursor, N);
    fill_csr<<<2048, 256, 0, stream>>>(src, dst, cursor, csr, E);

    const int gemm_grid = (N + 63) / 64;
    const int comb_grid = (N + 3) / 4;
    const int n4 = N * D / 4;

    // ---- layer 1: x0 -> x1 (fp16, pre-BN; BN1 folded into layer-2 weights) ----
    pack_weights<<<1, 256, 0, stream>>>(W0, Wr0, br0, nullptr, nullptr, Wp0, cadd0, brp0);
    gather_sum<<<comb_grid, 256, 0, stream>>>(x0_buf, csr, offsets, agg_buf, N);
    hipMemsetAsync(stats1, 0, 2048 * sizeof(float), stream);
    gemm_fused<true><<<gemm_grid, 256, 0, stream>>>(x0_buf, agg_buf, Wp0, cadd0, brp0,
                                                    b0, counts, x1_buf, stats1, N);
    bn_finalize<<<1, D, 0, stream>>>(stats1, g0, be0, invN);

    // ---- layer 2: x1 -> out (fp32 pre-BN2), BN1 folded into Wp1/cadd1/brp1 ----
    pack_weights<<<1, 256, 0, stream>>>(W1, Wr1, br1, stats1 + 2048, stats1 + 2048 + 128,
                                        Wp1, cadd1, brp1);
    gather_sum<<<comb_grid, 256, 0, stream>>>(x1_buf, csr, offsets, agg_buf, N);
    hipMemsetAsync(stats2, 0, 2048 * sizeof(float), stream);
    gemm_fused<false><<<gemm_grid, 256, 0, stream>>>(x1_buf, agg_buf, Wp1, cadd1, brp1,
                                                     b1, counts, out, stats2, N);
    bn_finalize<<<1, D, 0, stream>>>(stats2, g1, be1, invN);
    bn_apply<<<2048, 256, 0, stream>>>(out, stats2, n4);
}